// Round 5
// baseline (264.742 us; speedup 1.0000x reference)
//
#include <hip/hip_runtime.h>
#include <hip/hip_bf16.h>

// Shapes (fixed by the reference)
#define BB 4
#define SS 4096
#define EE 1024
#define DD 64
// rows = BB*SS = 16384

typedef unsigned short u16;
typedef unsigned int   u32;
typedef __bf16 bf16_t;
typedef bf16_t bf16x8 __attribute__((ext_vector_type(8)));
typedef bf16_t bf16x2 __attribute__((ext_vector_type(2)));
typedef float  f32x4  __attribute__((ext_vector_type(4)));
typedef u32    u32x4  __attribute__((ext_vector_type(4)));

__device__ __forceinline__ u16 f2bf(float f) {
    u32 u; __builtin_memcpy(&u, &f, 4);
    u32 r = (u + 0x7FFFu + ((u >> 16) & 1u)) >> 16;   // RNE
    return (u16)r;
}

// ---------------------------------------------------------------------------
// Prep 1: Wt[c][e] = bf16(W{q,k,v}[e][c&63])  (c in [0,192)) for B-frag loads
// ---------------------------------------------------------------------------
__global__ __launch_bounds__(256) void wt_kernel(const float* __restrict__ Wq,
                                                 const float* __restrict__ Wk,
                                                 const float* __restrict__ Wv,
                                                 u16* __restrict__ Wt) {
    int t = blockIdx.x * 256 + threadIdx.x;   // 0..196607
    int c = t >> 10, e = t & 1023;
    const float* W = (c < 64) ? Wq : (c < 128) ? Wk : Wv;
    Wt[c * 1024 + e] = f2bf(W[e * 64 + (c & 63)]);
}

// ---------------------------------------------------------------------------
// Prep 2: WoSum[d][e] = sum_h Wo[h*64+d][e]  (fp32) -- collapses head tiling
// ---------------------------------------------------------------------------
__global__ __launch_bounds__(256) void wosum_kernel(const float* __restrict__ Wo,
                                                    float* __restrict__ WoSum) {
    int t = blockIdx.x * 256 + threadIdx.x;   // 0..65535
    int d = t >> 10, e = t & 1023;
    float s = 0.f;
    #pragma unroll
    for (int h = 0; h < 16; h++) s += Wo[(h * 64 + d) * 1024 + e];
    WoSum[t] = s;
}

// ---------------------------------------------------------------------------
// QKV projection: [16384 x 1024] @ [1024 x 192], mfma 16x16x32 bf16.
// 512 blocks x 256 thr (4 waves); block = 32 rows x 192 cols.
// Q gets bias, then * 0.125 * log2(e)  (softmax scale + exp2 base-change
// folded in -- the fixed-shift cancels in p/sum(p) so attn uses raw exp2).
// ---------------------------------------------------------------------------
__global__ __launch_bounds__(256) void proj_kernel(const float* __restrict__ x,
                                                   const u16* __restrict__ Wtg,
                                                   const float* __restrict__ bq,
                                                   const float* __restrict__ bk,
                                                   const float* __restrict__ bv,
                                                   u16* __restrict__ Qg,
                                                   u16* __restrict__ Kg,
                                                   u16* __restrict__ Vtg) {
    __shared__ __align__(16) u16 xt[32 * 136];    // 8704 B
    __shared__ __align__(16) u16 wts[192 * 136];  // 52224 B

    const int tid  = threadIdx.x;
    const int w    = tid >> 6;
    const int lane = tid & 63;
    const int m    = lane & 15;
    const int quad = lane >> 4;
    const int r0   = blockIdx.x * 32;
    const int mt   = w & 1;       // m-tile within block
    const int ch   = w >> 1;      // column half (96 cols)

    f32x4 acc[6];
    #pragma unroll
    for (int i = 0; i < 6; i++) acc[i] = (f32x4){0.f, 0.f, 0.f, 0.f};

    f32x4 xr[4];
    u32x4 wr[12];

    auto preload = [&](int kb) {
        #pragma unroll
        for (int j = 0; j < 2; j++) {
            const int id = tid + j * 256, row = id >> 4, seg = id & 15;
            const float* src = x + (r0 + row) * 1024 + kb * 128 + seg * 8;
            xr[2 * j]     = *(const f32x4*)(src);
            xr[2 * j + 1] = *(const f32x4*)(src + 4);
        }
        #pragma unroll
        for (int j = 0; j < 12; j++) {
            const int id = tid + j * 256, row = id >> 4, seg = id & 15;
            wr[j] = *(const u32x4*)(Wtg + row * 1024 + kb * 128 + seg * 8);
        }
    };
    auto commit = [&]() {
        #pragma unroll
        for (int j = 0; j < 2; j++) {
            const int id = tid + j * 256, row = id >> 4, seg = id & 15;
            u32x4 p;
            p[0] = (u32)f2bf(xr[2*j][0])   | ((u32)f2bf(xr[2*j][1]) << 16);
            p[1] = (u32)f2bf(xr[2*j][2])   | ((u32)f2bf(xr[2*j][3]) << 16);
            p[2] = (u32)f2bf(xr[2*j+1][0]) | ((u32)f2bf(xr[2*j+1][1]) << 16);
            p[3] = (u32)f2bf(xr[2*j+1][2]) | ((u32)f2bf(xr[2*j+1][3]) << 16);
            *(u32x4*)(xt + row * 136 + seg * 8) = p;
        }
        #pragma unroll
        for (int j = 0; j < 12; j++) {
            const int id = tid + j * 256, row = id >> 4, seg = id & 15;
            *(u32x4*)(wts + row * 136 + seg * 8) = wr[j];
        }
    };

    preload(0);
    for (int kb = 0; kb < 8; kb++) {
        __syncthreads();
        commit();
        __syncthreads();
        if (kb < 7) preload(kb + 1);
        #pragma unroll
        for (int ks = 0; ks < 4; ks++) {
            bf16x8 a = *(const bf16x8*)(xt + (mt * 16 + m) * 136 + ks * 32 + quad * 8);
            #pragma unroll
            for (int c = 0; c < 6; c++) {
                bf16x8 b = *(const bf16x8*)(wts + (ch * 96 + c * 16 + m) * 136 + ks * 32 + quad * 8);
                acc[c] = __builtin_amdgcn_mfma_f32_16x16x32_bf16(a, b, acc[c], 0, 0, 0);
            }
        }
    }

    // Epilogue: C layout col=lane&15, row=quad*4+reg
    const float QSCALE = 0.125f * 1.4426950408889634f;   // 1/sqrt(64) * log2(e)
    const int rbase = r0 + mt * 16 + quad * 4;
    #pragma unroll
    for (int c = 0; c < 6; c++) {
        const int col   = ch * 96 + c * 16 + m;   // 0..191
        const int which = col >> 6;
        const int d     = col & 63;
        const float bias = (which == 0 ? bq : which == 1 ? bk : bv)[d];
        #pragma unroll
        for (int r = 0; r < 4; r++) {
            const int row = rbase + r;
            float v = acc[c][r] + bias;
            if (which == 0) {
                Qg[row * 64 + d] = f2bf(v * QSCALE);
            } else if (which == 1) {
                Kg[row * 64 + d] = f2bf(v);
            } else {
                const int b = row >> 12, s = row & 4095;
                Vtg[(b * 64 + d) * 4096 + s] = f2bf(v);    // transposed V
            }
        }
    }
}

// ---------------------------------------------------------------------------
// Flash attention v4: shared-tile blocks, full occupancy.
// Block = 256 thr (4 waves); each wave owns 16 of the block's 64 queries
// (disjoint => NO cross-wave merge). All waves share one double-buffered
// K/V LDS tile (single barrier per 32-key iter, m97-style). Keys split
// nks ways ACROSS blocks; unnormalized ctx partials + li written to ws,
// merged in out_kernel. Softmax: p = exp2(sc) -- log2e folded into Q,
// fixed shift cancels in normalization. LDS exactly 20480 B -> 8 blk/CU.
// ---------------------------------------------------------------------------
__global__ __launch_bounds__(256, 8) void attn_kernel(const u16* __restrict__ Qg,
                                                      const u16* __restrict__ Kg,
                                                      const u16* __restrict__ Vtg,
                                                      float* __restrict__ ctxP,
                                                      float* __restrict__ liP,
                                                      int nks, int ksh, int niter) {
    // u16 layout: K0 @0 [32k][64d], K1 @2048, V0 @4096 [64d][32k], V1 @6144,
    //             P @8192 [64q][32k] (chunk-swizzled). Total 10240 u16 = 20480 B.
    __shared__ __align__(16) u16 smem[10240];

    const int tid  = threadIdx.x;
    const int w    = tid >> 6;
    const int lane = tid & 63;
    const int m    = lane & 15;
    const int quad = lane >> 4;

    const int bi    = blockIdx.x;
    const int batch = (bi & 7) >> 1;                    // XCD-pair per batch
    const int j     = ((bi >> 3) << 1) | (bi & 1);
    const int qt    = j >> ksh;
    const int ks    = j & (nks - 1);
    const int qrow0 = batch * 4096 + qt * 64;
    const int kper  = 4096 >> ksh;
    const int kbase = ks * kper;

    // Q A-fragments (wave's 16 rows)
    bf16x8 aq0 = *(const bf16x8*)(Qg + (qrow0 + w * 16 + m) * 64 + quad * 8);
    bf16x8 aq1 = *(const bf16x8*)(Qg + (qrow0 + w * 16 + m) * 64 + 32 + quad * 8);

    f32x4 acc[4];
    #pragma unroll
    for (int c = 0; c < 4; c++) acc[c] = (f32x4){0.f, 0.f, 0.f, 0.f};
    float li[4] = {0.f, 0.f, 0.f, 0.f};

    const u16* Kbase = Kg + batch * 4096 * 64;
    const u16* Vbase = Vtg + batch * 64 * 4096;

    // staging roles
    const int rK = tid >> 3, sK = tid & 7;   // K: [32 rows][8 chunks]
    const int rV = tid >> 2, sV = tid & 3;   // V: [64 rows][4 chunks]
    const int sKp = (sK ^ (rK & 7)) * 8;
    const int sVp = (sV ^ ((rV >> 1) & 3)) * 8;

    u32x4 kr, vr;
    auto preload = [&](int it) {
        const int k0 = kbase + it * 32;
        kr = *(const u32x4*)(Kbase + (k0 + rK) * 64 + sK * 8);
        vr = *(const u32x4*)(Vbase + rV * 4096 + k0 + sV * 8);
    };
    auto commitKV = [&](int p) {
        *(u32x4*)(smem + p * 2048 + rK * 64 + sKp) = kr;
        *(u32x4*)(smem + 4096 + p * 2048 + rV * 32 + sVp) = vr;
    };

    // hoisted fragment addresses
    const int kph0 = (quad ^ (m & 7)) * 8;
    const int kph1 = ((quad | 4) ^ (m & 7)) * 8;
    const int vph  = (quad ^ ((m >> 1) & 3)) * 8;
    u16* Pb = smem + 8192;
    const u16* apAddr = Pb + (w * 16 + m) * 32 + vph;   // same swizzle form as V reads

    preload(0);
    commitKV(0);
    if (niter > 1) preload(1);
    __syncthreads();

    for (int it = 0; it < niter; it++) {
        const int cur = it & 1;
        u16* Kt = smem + cur * 2048;
        u16* Vt = smem + 4096 + cur * 2048;

        if (it + 1 < niter) commitKV((it + 1) & 1);   // other buffer; prev readers past barrier
        if (it + 2 < niter) preload(it + 2);

        // ---- QK^T: S[16q x 32k] per wave ----
        f32x4 sc[2];
        #pragma unroll
        for (int c = 0; c < 2; c++) {
            const int key = c * 16 + m;
            bf16x8 b0 = *(const bf16x8*)(Kt + key * 64 + kph0);
            bf16x8 b1 = *(const bf16x8*)(Kt + key * 64 + kph1);
            f32x4 t = __builtin_amdgcn_mfma_f32_16x16x32_bf16(aq0, b0, (f32x4){0.f,0.f,0.f,0.f}, 0, 0, 0);
            sc[c]   = __builtin_amdgcn_mfma_f32_16x16x32_bf16(aq1, b1, t, 0, 0, 0);
        }

        // ---- softmax: p = exp2(sc) (scale/shift pre-folded) + P write ----
        #pragma unroll
        for (int r = 0; r < 4; r++) {
            const float p0 = __builtin_exp2f(sc[0][r]);
            const float p1 = __builtin_exp2f(sc[1][r]);
            li[r] += p0 + p1;
            bf16x2 pk; pk[0] = (bf16_t)p0; pk[1] = (bf16_t)p1;
            u32 upk; __builtin_memcpy(&upk, &pk, 4);
            const int row = w * 16 + quad * 4 + r;
            const int rsw = (row >> 1) & 3;
            Pb[row * 32 + (((m >> 3) ^ rsw) << 3) + (m & 7)]       = (u16)upk;
            Pb[row * 32 + ((((m >> 3) | 2) ^ rsw) << 3) + (m & 7)] = (u16)(upk >> 16);
        }

        // ---- PV: ctx[16q x 64d] += P[16x32] @ V[32x64] ----
        bf16x8 ap = *(const bf16x8*)(apAddr);
        #pragma unroll
        for (int c = 0; c < 4; c++) {
            bf16x8 bv = *(const bf16x8*)(Vt + (c * 16 + m) * 32 + vph);
            acc[c] = __builtin_amdgcn_mfma_f32_16x16x32_bf16(ap, bv, acc[c], 0, 0, 0);
        }

        if (it + 1 < niter) __syncthreads();
    }

    // ---- li: reduce across the 16 m-lanes ----
    #pragma unroll
    for (int r = 0; r < 4; r++) {
        float v = li[r];
        v += __shfl_xor(v, 1);
        v += __shfl_xor(v, 2);
        v += __shfl_xor(v, 4);
        v += __shfl_xor(v, 8);
        li[r] = v;
    }

    // ---- write unnormalized partial + li ----
    const int p_idx = ((batch * 64 + qt) << ksh) + ks;
    float* cp = ctxP + p_idx * 4096 + w * 1024;
    #pragma unroll
    for (int c = 0; c < 4; c++)
        #pragma unroll
        for (int r = 0; r < 4; r++)
            cp[(quad * 4 + r) * 64 + c * 16 + m] = acc[c][r];
    if (m == 0) {
        #pragma unroll
        for (int r = 0; r < 4; r++)
            liP[p_idx * 64 + w * 16 + quad * 4 + r] = li[r];
    }
}

// ---------------------------------------------------------------------------
// Output v3: merge nks attention partials, normalize, then GEMM with WoSum.
// Grid 512 x 256 thr; block = 32 rows x full 1024 cols (eb loop).
// ---------------------------------------------------------------------------
__global__ __launch_bounds__(256) void out_kernel(const float* __restrict__ ctxP,
                                                  const float* __restrict__ liP,
                                                  const float* __restrict__ WoSum,
                                                  const float* __restrict__ bo,
                                                  float* __restrict__ out,
                                                  int nks) {
    __shared__ float cl[32 * 64];   // 8 KB
    __shared__ float lil[32];
    const int tid = threadIdx.x;
    const int bi  = blockIdx.x;           // 512 blocks, 32 rows each
    const int r0  = bi * 32;

    // merge partials (each thread: 8 floats = 2 f32x4)
    f32x4 s0 = (f32x4){0.f,0.f,0.f,0.f}, s1 = (f32x4){0.f,0.f,0.f,0.f};
    const int half = bi & 1;
    for (int ks = 0; ks < nks; ks++) {
        const float* src = ctxP + ((bi >> 1) * nks + ks) * 4096 + half * 2048 + tid * 8;
        s0 += *(const f32x4*)(src);
        s1 += *(const f32x4*)(src + 4);
    }
    if (tid < 32) {
        float L = 0.f;
        for (int ks = 0; ks < nks; ks++)
            L += liP[((bi >> 1) * nks + ks) * 64 + half * 32 + tid];
        lil[tid] = L;
    }
    __syncthreads();
    const float inv = 1.0f / lil[tid >> 3];     // row = tid*8/64
    *(f32x4*)(cl + tid * 8)     = s0 * inv;
    *(f32x4*)(cl + tid * 8 + 4) = s1 * inv;
    __syncthreads();

    // GEMM: 32 rows x 1024 cols
    const int rg = tid >> 6;            // 0..3 -> rows rg*8..+7
    const int cg = tid & 63;
    for (int eb = 0; eb < 4; eb++) {
        const int e0 = eb * 256 + cg * 4;
        f32x4 bo4 = *(const f32x4*)(bo + e0);
        f32x4 a[8];
        #pragma unroll
        for (int r = 0; r < 8; r++) a[r] = bo4;
        for (int d = 0; d < 64; d++) {
            f32x4 wv = *(const f32x4*)(WoSum + d * 1024 + e0);
            #pragma unroll
            for (int r = 0; r < 8; r++)
                a[r] += wv * cl[(rg * 8 + r) * 64 + d];
        }
        #pragma unroll
        for (int r = 0; r < 8; r++)
            *(f32x4*)(out + (r0 + rg * 8 + r) * 1024 + e0) = a[r];
    }
}

// ---------------------------------------------------------------------------
extern "C" void kernel_launch(void* const* d_in, const int* in_sizes, int n_in,
                              void* d_out, int out_size, void* d_ws, size_t ws_size,
                              hipStream_t stream) {
    const float* x  = (const float*)d_in[0];
    const float* Wq = (const float*)d_in[1];
    const float* bq = (const float*)d_in[2];
    const float* Wk = (const float*)d_in[3];
    const float* bk = (const float*)d_in[4];
    const float* Wv = (const float*)d_in[5];
    const float* bv = (const float*)d_in[6];
    const float* Wo = (const float*)d_in[7];
    const float* bo = (const float*)d_in[8];
    float* out = (float*)d_out;

    char* ws = (char*)d_ws;
    u16*   Wt   = (u16*)(ws);                 // 393216 B
    float* WoS  = (float*)(ws + 393216);      // 262144 B
    u16*   Qg   = (u16*)(ws + 655360);        // 2097152 B
    u16*   Kg   = (u16*)(ws + 2752512);       // 2097152 B
    u16*   Vtg  = (u16*)(ws + 4849664);       // 2097152 B
    float* ctxP = (float*)(ws + 6946816);     // nks*4194304 B
    // liP follows ctxP

    // key-split factor: 8 needs ~41 MB of ws; fall back to 1 (~11.2 MB) if tight
    const int nks   = (ws_size >= (size_t)6946816 + 8u * 4259840u) ? 8 : 1;
    const int ksh   = (nks == 8) ? 3 : 0;
    const int niter = 128 >> ksh;
    float* liP = (float*)(ws + 6946816 + (size_t)nks * 4194304u);

    wt_kernel   <<<768,  256, 0, stream>>>(Wq, Wk, Wv, Wt);
    wosum_kernel<<<256,  256, 0, stream>>>(Wo, WoS);
    proj_kernel <<<512,  256, 0, stream>>>(x, Wt, bq, bk, bv, Qg, Kg, Vtg);
    attn_kernel <<<256 * nks, 256, 0, stream>>>(Qg, Kg, Vtg, ctxP, liP, nks, ksh, niter);
    out_kernel  <<<512,  256, 0, stream>>>(ctxP, liP, WoS, bo, out, nks);
}